// Round 8
// baseline (109.800 us; speedup 1.0000x reference)
//
#include <hip/hip_runtime.h>
#include <hip/hip_bf16.h>
#include <stdint.h>

#define TOKENS 2048
#define DD 1024
#define HH 2048
#define NE 8
#define RP_CAP 3072   // padded-row capacity
#define BM 64
#define BN 64
#define BK 64

typedef float f32x4 __attribute__((ext_vector_type(4)));
typedef short bf16x8 __attribute__((ext_vector_type(8)));
typedef unsigned int u32;

__device__ __forceinline__ unsigned short f2bf(float f) {
    union { float f; u32 u; } v; v.f = f;
    u32 u = v.u;
    return (unsigned short)((u + 0x7fffu + ((u >> 16) & 1u)) >> 16);
}

// ---------------- routing: expert per token, padded segments (64-aligned), perm ----------------
__global__ __launch_bounds__(256) void k_route(const int* __restrict__ orig,
                                               const int* __restrict__ hmap,
                                               int* __restrict__ hdr) {
    __shared__ int s_e[TOKENS];
    __shared__ int s_cnt[NE];
    __shared__ int s_off[NE];
    int tid = threadIdx.x;
    if (tid < NE) s_cnt[tid] = 0;
    __syncthreads();
    for (int t = tid; t < TOKENS; t += 256) {
        int e = hmap[orig[t]];
        s_e[t] = e;
        atomicAdd(&s_cnt[e], 1);
    }
    __syncthreads();
    if (tid == 0) {
        int run = 0;
        for (int e = 0; e < NE; ++e) {
            s_off[e] = run;
            hdr[e] = s_cnt[e];
            hdr[8 + e] = run;
            run += ((s_cnt[e] + BM - 1) / BM) * BM;
        }
        hdr[16] = run;
    }
    __syncthreads();
    int* perm = hdr + 64;
    for (int r = tid; r < RP_CAP; r += 256) perm[r] = -1;
    if (tid < NE) s_cnt[tid] = 0;
    __syncthreads();
    for (int t = tid; t < TOKENS; t += 256) {
        int e = s_e[t];
        int pos = s_off[e] + atomicAdd(&s_cnt[e], 1);
        perm[pos] = t;
    }
}

// ---------------- gather x -> bf16 permuted padded layout ----------------
__global__ __launch_bounds__(256) void k_gather(const float* __restrict__ x,
                                                const int* __restrict__ hdr,
                                                unsigned short* __restrict__ xp) {
    int r = blockIdx.x;
    int t = hdr[64 + r];  // perm
    int tid = threadIdx.x;
    ushort4* dst = (ushort4*)(xp + (size_t)r * DD);
    if (t >= 0) {
        const float4* src = (const float4*)(x + (size_t)t * DD);
        float4 v = src[tid];
        ushort4 o;
        o.x = f2bf(v.x); o.y = f2bf(v.y); o.z = f2bf(v.z); o.w = f2bf(v.w);
        dst[tid] = o;
    } else {
        ushort4 z; z.x = 0; z.y = 0; z.z = 0; z.w = 0;
        dst[tid] = z;
    }
}

// ---------------- grouped GEMM: C = A(bf16,[RP][K]) * W(f32,[NE][N][K])^T ----------------
// n-group tiling: block = 64 rows x (NG*64) cols. Per K-step window:
//   issue-early { STAGE_A(next) 2x gload_lds + B_LOAD(next) NG*4 f32 loads }
//   -> COMPUTE (2*NG*4 = fat MFMA phase, A frags hoisted across subs)
//   -> write-late B_WRITE(next) -> s_waitcnt vmcnt(0) lgkmcnt(0) -> s_barrier.
// Single full drain per window (r1-proven protocol) amortized over a ~NG*16-MFMA
// compute phase that also hides the load latency (T14 issue-early/write-late).
template<int KDIM, int NDIM, int NG, int MINW, bool L2EPI>
__global__ __launch_bounds__(256, MINW) void k_gemm(const unsigned short* __restrict__ A,
                                                    const float* __restrict__ W,
                                                    const float* __restrict__ bias,
                                                    const int* __restrict__ hdr,
                                                    unsigned short* __restrict__ hout,
                                                    float* __restrict__ out) {
    int total = hdr[16];
    int row0 = blockIdx.y * BM;
    if (row0 >= total) return;
    int e = 0;
#pragma unroll
    for (int i = 1; i < NE; ++i)
        if (row0 >= hdr[8 + i]) e = i;

    int n0 = blockIdx.x * (BN * NG);
    const float* We = W + (size_t)e * NDIM * KDIM;
    const float* be = bias + (size_t)e * NDIM;

    constexpr int ASZ = BM * BK;   // 4096 elems (8 KB)
    constexpr int BSZ = BN * BK;   // 4096 elems (8 KB)
    __shared__ __align__(16) unsigned short As[2 * ASZ];        // 16 KB
    __shared__ __align__(16) unsigned short Bs[2 * NG * BSZ];   // 2*NG*8 KB

    int tid = threadIdx.x;
    int w = tid >> 6, lane = tid & 63;
    int wr = w >> 1, wc = w & 1;          // wave grid 2M x 2N (32x32 per wave per sub)
    int fr = lane & 15, hi = lane >> 4;

    f32x4 acc[NG][2][2];
#pragma unroll
    for (int s = 0; s < NG; ++s)
#pragma unroll
        for (int m = 0; m < 2; ++m)
#pragma unroll
            for (int n = 0; n < 2; ++n) acc[s][m][n] = f32x4{0.f, 0.f, 0.f, 0.f};

    float4 bv[NG][4];   // B reg stage (fully unrolled -> static indexing)

    auto STAGE_A = [&](int buf, int k0) {
#pragma unroll
        for (int j = 0; j < 2; ++j) {
            int c = j * 256 + tid;          // 16B chunk id in [0,512)
            int row = c >> 3;               // [0,64)
            int slot = c & 7;
            int gslot = slot ^ (row & 7);   // inverse-swizzled source slot
            const unsigned short* gp = A + (size_t)(row0 + row) * KDIM + k0 + gslot * 8;
            unsigned short* lp = (unsigned short*)As + buf * ASZ + j * 2048 + w * 512;
            __builtin_amdgcn_global_load_lds((const __attribute__((address_space(1))) u32*)gp,
                                             (__attribute__((address_space(3))) u32*)lp, 16, 0, 0);
        }
    };
    auto B_LOAD_ALL = [&](int k0) {
#pragma unroll
        for (int s = 0; s < NG; ++s) {
#pragma unroll
            for (int jr = 0; jr < 2; ++jr) {
                int c = jr * 256 + tid;         // 8-f32 group id in [0,512)
                int row = c >> 3;               // [0,64)
                int cl = c & 7;
                const float4* gp = (const float4*)(We + (size_t)(n0 + s * BN + row) * KDIM + k0 + cl * 8);
                bv[s][jr * 2]     = gp[0];
                bv[s][jr * 2 + 1] = gp[1];
            }
        }
    };
    auto B_WRITE_ALL = [&](int buf) {
#pragma unroll
        for (int s = 0; s < NG; ++s) {
            unsigned short* Bb = Bs + (buf * NG + s) * BSZ;
#pragma unroll
            for (int jr = 0; jr < 2; ++jr) {
                int c = jr * 256 + tid;
                int row = c >> 3;
                int cl = c & 7;
                float4 v0 = bv[s][jr * 2], v1 = bv[s][jr * 2 + 1];
                union { bf16x8 v; unsigned short sv[8]; } o;
                o.sv[0] = f2bf(v0.x); o.sv[1] = f2bf(v0.y); o.sv[2] = f2bf(v0.z); o.sv[3] = f2bf(v0.w);
                o.sv[4] = f2bf(v1.x); o.sv[5] = f2bf(v1.y); o.sv[6] = f2bf(v1.z); o.sv[7] = f2bf(v1.w);
                int sp = cl ^ (row & 7);
                *(bf16x8*)&Bb[row * 64 + sp * 8] = o.v;
            }
        }
    };
    auto COMPUTE_ALL = [&](int buf) {
        const unsigned short* Ab = As + buf * ASZ;
#pragma unroll
        for (int kk = 0; kk < BK; kk += 32) {
            bf16x8 af[2];
#pragma unroll
            for (int m = 0; m < 2; ++m) {
                int rr = wr * 32 + m * 16 + fr;
                int idx = (rr * 64 + kk + hi * 8) ^ ((rr & 7) << 3);
                af[m] = *(const bf16x8*)&Ab[idx];
            }
#pragma unroll
            for (int s = 0; s < NG; ++s) {
                const unsigned short* Bb = Bs + (buf * NG + s) * BSZ;
                bf16x8 bfr[2];
#pragma unroll
                for (int n = 0; n < 2; ++n) {
                    int cn = wc * 32 + n * 16 + fr;
                    int idx = (cn * 64 + kk + hi * 8) ^ ((cn & 7) << 3);
                    bfr[n] = *(const bf16x8*)&Bb[idx];
                }
#pragma unroll
                for (int m = 0; m < 2; ++m)
#pragma unroll
                    for (int n = 0; n < 2; ++n)
                        acc[s][m][n] = __builtin_amdgcn_mfma_f32_16x16x32_bf16(af[m], bfr[n], acc[s][m][n], 0, 0, 0);
            }
        }
    };

    constexpr int NT = KDIM / BK;

#define WAIT_ALL0 asm volatile("s_waitcnt vmcnt(0) lgkmcnt(0)" ::: "memory")
#define BARRIER   do { __builtin_amdgcn_s_barrier(); asm volatile("" ::: "memory"); } while (0)

    // prologue: tile 0 into buf 0
    STAGE_A(0, 0);
    B_LOAD_ALL(0);
    B_WRITE_ALL(0);
    WAIT_ALL0;
    BARRIER;

    for (int t = 0; t < NT; ++t) {
        int buf = t & 1;
        if (t + 1 < NT) {               // wave-uniform guard
            STAGE_A(buf ^ 1, (t + 1) * BK);   // issue-early
            B_LOAD_ALL((t + 1) * BK);         // issue-early
        }
        COMPUTE_ALL(buf);                     // fat MFMA phase hides the loads
        if (t + 1 < NT) {
            B_WRITE_ALL(buf ^ 1);             // write-late (reg-waits land here)
            WAIT_ALL0;                        // drain A-stage + everything
            BARRIER;
        }
    }
#undef WAIT_ALL0
#undef BARRIER

    // ---- epilogue ----
    const int* perm = hdr + 64;
    int rbase = row0 + wr * 32 + hi * 4;
#pragma unroll
    for (int s = 0; s < NG; ++s) {
        int cbase = n0 + s * BN + wc * 32 + fr;
        if constexpr (!L2EPI) {
#pragma unroll
            for (int n = 0; n < 2; ++n) {
                int cg = cbase + n * 16;
                float bvv = be[cg];
#pragma unroll
                for (int m = 0; m < 2; ++m) {
                    int rg = rbase + m * 16;
#pragma unroll
                    for (int r = 0; r < 4; ++r) {
                        float v = acc[s][m][n][r] + bvv;
                        v = v > 0.f ? v : 0.f;
                        hout[(size_t)(rg + r) * NDIM + cg] = f2bf(v);
                    }
                }
            }
        } else {
            float bvv[2];
#pragma unroll
            for (int n = 0; n < 2; ++n) bvv[n] = be[cbase + n * 16];
#pragma unroll
            for (int m = 0; m < 2; ++m) {
                int rg = rbase + m * 16;
#pragma unroll
                for (int r = 0; r < 4; ++r) {
                    int tk = perm[rg + r];
                    if (tk < 0) continue;
                    float* op = out + (size_t)tk * DD;
#pragma unroll
                    for (int n = 0; n < 2; ++n)
                        op[cbase + n * 16] = acc[s][m][n][r] + bvv[n];
                }
            }
        }
    }
}

extern "C" void kernel_launch(void* const* d_in, const int* in_sizes, int n_in,
                              void* d_out, int out_size, void* d_ws, size_t ws_size,
                              hipStream_t stream) {
    const float* x    = (const float*)d_in[0];
    const int*   orig = (const int*)d_in[1];
    const int*   hmap = (const int*)d_in[2];
    const float* W1   = (const float*)d_in[3];
    const float* b1   = (const float*)d_in[4];
    const float* W2   = (const float*)d_in[5];
    const float* b2   = (const float*)d_in[6];
    float* out = (float*)d_out;

    int* hdr = (int*)d_ws;
    unsigned short* xp   = (unsigned short*)((char*)d_ws + 16384);
    unsigned short* hbuf = (unsigned short*)((char*)d_ws + 16384 + (size_t)RP_CAP * DD * 2);

    k_route<<<1, 256, 0, stream>>>(orig, hmap, hdr);
    k_gather<<<RP_CAP, 256, 0, stream>>>(x, hdr, xp);
    // grid.x = 8 col-groups -> one weight panel per XCD (idx % 8 = x)
    k_gemm<DD, HH, 4, 2, false><<<dim3(HH / (BN * 4), RP_CAP / BM), 256, 0, stream>>>(xp, W1, b1, hdr, hbuf, nullptr);
    k_gemm<HH, DD, 2, 3, true><<<dim3(DD / (BN * 2), RP_CAP / BM), 256, 0, stream>>>(hbuf, W2, b2, hdr, nullptr, out);
}